// Round 1
// baseline (1110.526 us; speedup 1.0000x reference)
//
#include <hip/hip_runtime.h>

// ---------------- problem constants ----------------
#define NB    2
#define QLEN  512
#define HIDD  5120
#define QLORA 1536
#define NHEAD 128
#define QHD   192
#define VHD   128
#define KVTOT 1024
#define MROWS 1024  // NB*QLEN

typedef float          f32x4   __attribute__((ext_vector_type(4)));
typedef __bf16         bf16x8  __attribute__((ext_vector_type(8)));
typedef unsigned short u16x8   __attribute__((ext_vector_type(8)));
typedef unsigned short u16x4   __attribute__((ext_vector_type(4)));
typedef float          f32x4v  __attribute__((ext_vector_type(4)));

static __device__ __forceinline__ unsigned short f2bf(float f) {
  union { float f; unsigned u; } v; v.f = f;
  return (unsigned short)((v.u + 0x7fffu + ((v.u >> 16) & 1u)) >> 16);
}

static __device__ __forceinline__ void g2l16(const void* g, void* l) {
  __builtin_amdgcn_global_load_lds(
      (const __attribute__((address_space(1))) void*)g,
      (__attribute__((address_space(3))) void*)l, 16, 0, 0);
}

// ---------------- f32 -> bf16 convert ----------------
__global__ __launch_bounds__(256) void cvt_bf16_k(const float* __restrict__ in,
                                                  unsigned short* __restrict__ out,
                                                  long n4) {
  long i = (long)blockIdx.x * 256 + threadIdx.x;
  if (i >= n4) return;
  f32x4 v = *(const f32x4*)(in + i * 4);
  u16x4 o;
  o[0] = f2bf(v[0]); o[1] = f2bf(v[1]); o[2] = f2bf(v[2]); o[3] = f2bf(v[3]);
  *(u16x4*)(out + i * 4) = o;
}

// ---------------- rmsnorm (one block per row) ----------------
__global__ __launch_bounds__(256) void rmsnorm_k(const float* __restrict__ in,
                                                 int instride, int cols,
                                                 const float* __restrict__ g,
                                                 unsigned short* __restrict__ out) {
  int row = blockIdx.x;
  int t = threadIdx.x, w = t >> 6, l = t & 63;
  const float* x = in + (long)row * instride;
  float xv[6];
  int nc = cols >> 8;  // cols/256 (6 or 2)
  float ss = 0.f;
  for (int i = 0; i < nc; ++i) { xv[i] = x[t + i * 256]; ss += xv[i] * xv[i]; }
  #pragma unroll
  for (int m = 32; m >= 1; m >>= 1) ss += __shfl_xor(ss, m);
  __shared__ float red[4];
  if (l == 0) red[w] = ss;
  __syncthreads();
  float tot = red[0] + red[1] + red[2] + red[3];
  float rs = rsqrtf(tot / (float)cols + 1e-6f);
  for (int i = 0; i < nc; ++i) {
    int c = t + i * 256;
    out[(long)row * cols + c] = f2bf(g[c] * xv[i] * rs);
  }
}

// ---------------- bf16 B^T GEMM, 128x128 tile, BK=64, 4 waves ----------------
// EPI 0: o0[row*N+col] = v  (f32)
// EPI 1: u0 = Q ws bf16, layout [b][h][qi][QHD]   (col = h*QHD+d, row = b*QLEN+qi)
// EPI 2: col = h*256+d: d<128 -> key f32 o0 + bf16 u0 at [b][h][512+qi][QHD]+d
//                       d>=128 -> value f32 o1 at [b][h][512+qi][VHD]+(d-128)
template <int EPI>
__global__ __launch_bounds__(256) void gemm_bt(const unsigned short* __restrict__ A,
                                               const unsigned short* __restrict__ Bm,
                                               int K, int N,
                                               float* __restrict__ o0,
                                               float* __restrict__ o1,
                                               unsigned short* __restrict__ u0) {
  __shared__ __align__(16) unsigned short sA[128 * 64];
  __shared__ __align__(16) unsigned short sB[128 * 64];
  const int t = threadIdx.x;
  const int w = t >> 6, l = t & 63;
  const int l15 = l & 15, lh = l >> 4;
  const int wm = w >> 1, wn = w & 1;
  const int mb = blockIdx.y, nb = blockIdx.x;
  const unsigned short* Ab = A + (long)mb * 128 * K;
  const unsigned short* Bb = Bm + (long)nb * 128 * K;
  f32x4 acc[4][4];
  #pragma unroll
  for (int i = 0; i < 4; ++i)
    #pragma unroll
    for (int j = 0; j < 4; ++j)
      #pragma unroll
      for (int r = 0; r < 4; ++r) acc[i][j][r] = 0.f;

  const int srow = l >> 3;         // row within 8-row chunk
  const int scol = (l & 7) * 8;    // element offset within row

  for (int kt = 0; kt < K; kt += 64) {
    #pragma unroll
    for (int i = 0; i < 4; ++i) {
      const int chunk = i * 4 + w;
      const int r = chunk * 8 + srow;
      g2l16(Ab + (long)r * K + kt + scol, (char*)sA + chunk * 1024);
      g2l16(Bb + (long)r * K + kt + scol, (char*)sB + chunk * 1024);
    }
    __syncthreads();
    #pragma unroll
    for (int ks = 0; ks < 2; ++ks) {
      bf16x8 af[4], bfr[4];
      #pragma unroll
      for (int i = 0; i < 4; ++i)
        af[i] = *(const bf16x8*)(sA + (wm * 64 + i * 16 + l15) * 64 + ks * 32 + lh * 8);
      #pragma unroll
      for (int j = 0; j < 4; ++j)
        bfr[j] = *(const bf16x8*)(sB + (wn * 64 + j * 16 + l15) * 64 + ks * 32 + lh * 8);
      #pragma unroll
      for (int i = 0; i < 4; ++i)
        #pragma unroll
        for (int j = 0; j < 4; ++j)
          acc[i][j] = __builtin_amdgcn_mfma_f32_16x16x32_bf16(af[i], bfr[j], acc[i][j], 0, 0, 0);
    }
    __syncthreads();
  }

  const long rowbase = (long)mb * 128 + wm * 64;
  const int colbase = nb * 128 + wn * 64;
  #pragma unroll
  for (int i = 0; i < 4; ++i) {
    #pragma unroll
    for (int j = 0; j < 4; ++j) {
      const int col = colbase + j * 16 + l15;
      #pragma unroll
      for (int r4 = 0; r4 < 4; ++r4) {
        const long row = rowbase + i * 16 + lh * 4 + r4;
        const float v = acc[i][j][r4];
        if (EPI == 0) {
          o0[row * N + col] = v;
        } else if (EPI == 1) {
          const int h = col / QHD, d = col - h * QHD;
          const long b_ = row >> 9, qi = row & 511;
          u0[(((b_ * NHEAD + h) * QLEN + qi)) * QHD + d] = f2bf(v);
        } else {
          const int h = col >> 8, d = col & 255;
          const long b_ = row >> 9, qi = row & 511;
          if (d < 128) {
            const long idx = ((b_ * NHEAD + h) * KVTOT + 512 + qi) * QHD + d;
            o0[idx] = v;
            u0[idx] = f2bf(v);
          } else {
            o1[((b_ * NHEAD + h) * KVTOT + 512 + qi) * VHD + (d - 128)] = v;
          }
        }
      }
    }
  }
}

// ---------------- past key copy: f32 out + bf16 ws ----------------
__global__ __launch_bounds__(256) void copy_key_past_k(const float* __restrict__ pk,
                                                       float* __restrict__ kout,
                                                       unsigned short* __restrict__ kb) {
  long i4 = (long)blockIdx.x * 256 + threadIdx.x;
  f32x4 v = *(const f32x4*)(pk + i4 * 4);
  long e = i4 * 4;
  long bh = e / 98304;            // 512*192
  long rem = e - bh * 98304;
  long oidx = bh * 196608 + rem;  // 1024*192
  *(f32x4*)(kout + oidx) = v;
  u16x4 b;
  b[0] = f2bf(v[0]); b[1] = f2bf(v[1]); b[2] = f2bf(v[2]); b[3] = f2bf(v[3]);
  *(u16x4*)(kb + oidx) = b;
}

// ---------------- past value copy: f32 out ----------------
__global__ __launch_bounds__(256) void copy_val_past_k(const float* __restrict__ pv,
                                                       float* __restrict__ vout) {
  long i4 = (long)blockIdx.x * 256 + threadIdx.x;
  f32x4 v = *(const f32x4*)(pv + i4 * 4);
  long e = i4 * 4;
  long bh = e / 65536;            // 512*128
  long rem = e - bh * 65536;
  *(f32x4*)(vout + bh * 131072 + rem) = v;
}

// ---------------- k_pe broadcast into key output (all heads) ----------------
__global__ __launch_bounds__(256) void kpe_bcast_k(const float* __restrict__ ckv,
                                                   float* __restrict__ kout,
                                                   unsigned short* __restrict__ kb) {
  int bq = blockIdx.x;  // b*512+qi
  long b_ = bq >> 9, qi = bq & 511;
  int t = threadIdx.x;
  int j = t & 63, h0 = t >> 6;
  float v = ckv[(long)bq * 640 + 512 + j];
  unsigned short vb = f2bf(v);
  for (int h = h0; h < NHEAD; h += 4) {
    long idx = ((b_ * NHEAD + h) * KVTOT + 512 + qi) * QHD + 128 + j;
    kout[idx] = v;
    kb[idx] = vb;
  }
}

// ---------------- V transpose: Vout f32 [bh][1024][128] -> Vt bf16 [bh][128][1024] ----------------
__global__ __launch_bounds__(256) void transpose_v_k(const float* __restrict__ vout,
                                                     unsigned short* __restrict__ vt) {
  __shared__ __align__(16) unsigned short sT[128 * 72];
  int bh = blockIdx.x >> 4, kt = blockIdx.x & 15;
  int t = threadIdx.x;
  #pragma unroll
  for (int i = 0; i < 8; ++i) {  // 2048 float4 chunks of [64 kv][128 d]
    int id = t + i * 256;
    int r = id >> 5, c4 = (id & 31) * 4;
    f32x4 v = *(const f32x4*)(vout + ((long)bh * KVTOT + kt * 64 + r) * VHD + c4);
    #pragma unroll
    for (int jj = 0; jj < 4; ++jj) sT[(c4 + jj) * 72 + r] = f2bf(v[jj]);
  }
  __syncthreads();
  #pragma unroll
  for (int i = 0; i < 4; ++i) {  // 1024 16B out chunks
    int id = t + i * 256;
    int d = id >> 3, c = id & 7;
    u16x8 v = *(const u16x8*)(sT + d * 72 + c * 8);
    *(u16x8*)(vt + ((long)bh * VHD + d) * KVTOT + kt * 64 + c * 8) = v;
  }
}

// ---------------- flash attention: 1 block = (b,h, 128-row q tile), 4 waves ----------------
__global__ __launch_bounds__(256, 2) void attn_k(const unsigned short* __restrict__ Qw,
                                                 const unsigned short* __restrict__ Kb,
                                                 const unsigned short* __restrict__ Vt,
                                                 const float* __restrict__ mask,
                                                 float* __restrict__ outp) {
  __shared__ __align__(16) unsigned short sK[64 * 200];
  __shared__ __align__(16) unsigned short sV[128 * 72];
  __shared__ __align__(16) unsigned short sP[128 * 72];
  const int t = threadIdx.x, w = t >> 6, l = t & 63;
  const int l15 = l & 15, lh = l >> 4;
  const int bh = blockIdx.x >> 2, qt = blockIdx.x & 3;
  const long b_ = bh >> 7;
  const float SCALE = 0.051023330039633184f;

  bf16x8 qf[2][6];
  const unsigned short* Qb = Qw + ((long)bh * QLEN + qt * 128 + w * 32) * QHD;
  #pragma unroll
  for (int i = 0; i < 2; ++i)
    #pragma unroll
    for (int ks = 0; ks < 6; ++ks)
      qf[i][ks] = *(const bf16x8*)(Qb + (i * 16 + l15) * QHD + ks * 32 + lh * 8);

  f32x4 o[2][8];
  #pragma unroll
  for (int i = 0; i < 2; ++i)
    #pragma unroll
    for (int j = 0; j < 8; ++j)
      #pragma unroll
      for (int r = 0; r < 4; ++r) o[i][j][r] = 0.f;
  float m_[2][4], l_[2][4];
  #pragma unroll
  for (int i = 0; i < 2; ++i)
    #pragma unroll
    for (int r = 0; r < 4; ++r) { m_[i][r] = -1e30f; l_[i][r] = 0.f; }

  const long maskbase = b_ * 524288;  // 512*1024
  const int qrow0 = qt * 128 + w * 32;

  for (int kt = 0; kt < 16; ++kt) {
    // stage K tile [64][192] bf16 -> sK (pad 200)
    #pragma unroll
    for (int i = 0; i < 6; ++i) {
      int id = t + i * 256;
      int r = id / 24, c = id - r * 24;
      *(u16x8*)(sK + r * 200 + c * 8) =
          *(const u16x8*)(Kb + ((long)bh * KVTOT + kt * 64 + r) * QHD + c * 8);
    }
    // stage Vt tile [128][64] -> sV (pad 72)
    #pragma unroll
    for (int i = 0; i < 4; ++i) {
      int id = t + i * 256;
      int r = id >> 3, c = id & 7;
      *(u16x8*)(sV + r * 72 + c * 8) =
          *(const u16x8*)(Vt + ((long)bh * VHD + r) * KVTOT + kt * 64 + c * 8);
    }
    __syncthreads();

    // S = Q K^T
    f32x4 s[2][4];
    #pragma unroll
    for (int i = 0; i < 2; ++i)
      #pragma unroll
      for (int j = 0; j < 4; ++j)
        #pragma unroll
        for (int r = 0; r < 4; ++r) s[i][j][r] = 0.f;
    #pragma unroll
    for (int j = 0; j < 4; ++j) {
      #pragma unroll
      for (int ks = 0; ks < 6; ++ks) {
        bf16x8 kf = *(const bf16x8*)(sK + (j * 16 + l15) * 200 + ks * 32 + lh * 8);
        s[0][j] = __builtin_amdgcn_mfma_f32_16x16x32_bf16(qf[0][ks], kf, s[0][j], 0, 0, 0);
        s[1][j] = __builtin_amdgcn_mfma_f32_16x16x32_bf16(qf[1][ks], kf, s[1][j], 0, 0, 0);
      }
    }

    // online softmax (D layout: row=(lane>>4)*4+reg, col=lane&15)
    #pragma unroll
    for (int i = 0; i < 2; ++i) {
      #pragma unroll
      for (int rg = 0; rg < 4; ++rg) {
        int qr = qrow0 + i * 16 + lh * 4 + rg;
        float sc[4];
        #pragma unroll
        for (int j = 0; j < 4; ++j)
          sc[j] = s[i][j][rg] * SCALE +
                  mask[maskbase + (long)qr * 1024 + kt * 64 + j * 16 + l15];
        float mx = fmaxf(fmaxf(sc[0], sc[1]), fmaxf(sc[2], sc[3]));
        mx = fmaxf(mx, __shfl_xor(mx, 1));
        mx = fmaxf(mx, __shfl_xor(mx, 2));
        mx = fmaxf(mx, __shfl_xor(mx, 4));
        mx = fmaxf(mx, __shfl_xor(mx, 8));
        float mo = m_[i][rg];
        float mn = fmaxf(mo, mx);
        float al = __expf(mo - mn);
        float rs = 0.f;
        int prow = w * 32 + i * 16 + lh * 4 + rg;
        #pragma unroll
        for (int j = 0; j < 4; ++j) {
          float p = __expf(sc[j] - mn);
          rs += p;
          sP[prow * 72 + j * 16 + l15] = f2bf(p);
        }
        rs += __shfl_xor(rs, 1);
        rs += __shfl_xor(rs, 2);
        rs += __shfl_xor(rs, 4);
        rs += __shfl_xor(rs, 8);
        l_[i][rg] = l_[i][rg] * al + rs;
        m_[i][rg] = mn;
        #pragma unroll
        for (int jj = 0; jj < 8; ++jj) o[i][jj][rg] *= al;
      }
    }
    __syncthreads();

    // O += P V
    #pragma unroll
    for (int ks = 0; ks < 2; ++ks) {
      bf16x8 pf0 = *(const bf16x8*)(sP + (w * 32 + l15) * 72 + ks * 32 + lh * 8);
      bf16x8 pf1 = *(const bf16x8*)(sP + (w * 32 + 16 + l15) * 72 + ks * 32 + lh * 8);
      #pragma unroll
      for (int jj = 0; jj < 8; ++jj) {
        bf16x8 vf = *(const bf16x8*)(sV + (jj * 16 + l15) * 72 + ks * 32 + lh * 8);
        o[0][jj] = __builtin_amdgcn_mfma_f32_16x16x32_bf16(pf0, vf, o[0][jj], 0, 0, 0);
        o[1][jj] = __builtin_amdgcn_mfma_f32_16x16x32_bf16(pf1, vf, o[1][jj], 0, 0, 0);
      }
    }
    __syncthreads();
  }

  #pragma unroll
  for (int i = 0; i < 2; ++i) {
    #pragma unroll
    for (int rg = 0; rg < 4; ++rg) {
      float inv = 1.0f / l_[i][rg];
      long row = (long)bh * QLEN + qrow0 + i * 16 + lh * 4 + rg;
      #pragma unroll
      for (int jj = 0; jj < 8; ++jj)
        outp[row * VHD + jj * 16 + l15] = o[i][jj][rg] * inv;
    }
  }
}

// ---------------- workspace layout (bytes) ----------------
#define WS_HID_BF   0L
#define WS_WQA_BF   10485760L
#define WS_WQB_BF   26214400L
#define WS_WKVA_BF  101711872L
#define WS_WKVB_BF  108265472L
#define WS_QA_F32   141819904L
#define WS_QAN_BF   148111360L
#define WS_CKV_F32  151257088L
#define WS_CKVN_BF  153878528L
#define WS_Q_BF     154927104L
#define WS_KB_BF    205258752L
#define WS_VT_BF    305922048L
// total 373030912 bytes

extern "C" void kernel_launch(void* const* d_in, const int* in_sizes, int n_in,
                              void* d_out, int out_size, void* d_ws, size_t ws_size,
                              hipStream_t stream) {
  const float* hs   = (const float*)d_in[0];
  const float* mask = (const float*)d_in[1];
  const float* pk   = (const float*)d_in[2];
  const float* pv   = (const float*)d_in[3];
  const float* wqa  = (const float*)d_in[4];
  const float* gqa  = (const float*)d_in[5];
  const float* wqb  = (const float*)d_in[6];
  const float* wkva = (const float*)d_in[7];
  const float* gkva = (const float*)d_in[8];
  const float* wkvb = (const float*)d_in[9];

  char* ws = (char*)d_ws;
  unsigned short* hid_bf  = (unsigned short*)(ws + WS_HID_BF);
  unsigned short* wqa_bf  = (unsigned short*)(ws + WS_WQA_BF);
  unsigned short* wqb_bf  = (unsigned short*)(ws + WS_WQB_BF);
  unsigned short* wkva_bf = (unsigned short*)(ws + WS_WKVA_BF);
  unsigned short* wkvb_bf = (unsigned short*)(ws + WS_WKVB_BF);
  float*          qa_f    = (float*)(ws + WS_QA_F32);
  unsigned short* qan_bf  = (unsigned short*)(ws + WS_QAN_BF);
  float*          ckv_f   = (float*)(ws + WS_CKV_F32);
  unsigned short* ckvn_bf = (unsigned short*)(ws + WS_CKVN_BF);
  unsigned short* q_bf    = (unsigned short*)(ws + WS_Q_BF);
  unsigned short* kb_bf   = (unsigned short*)(ws + WS_KB_BF);
  unsigned short* vt_bf   = (unsigned short*)(ws + WS_VT_BF);

  float* out_attn = (float*)d_out;
  float* out_key  = (float*)d_out + 16777216;
  float* out_val  = (float*)d_out + 67108864;

  // 1. converts
  cvt_bf16_k<<<5120, 256, 0, stream>>>(hs,   hid_bf,  1310720);
  cvt_bf16_k<<<7680, 256, 0, stream>>>(wqa,  wqa_bf,  1966080);
  cvt_bf16_k<<<36864, 256, 0, stream>>>(wqb, wqb_bf,  9437184);
  hipMemsetAsync(ws + WS_WKVA_BF + (long)576 * 5120 * 2, 0, (long)64 * 5120 * 2, stream);
  cvt_bf16_k<<<2880, 256, 0, stream>>>(wkva, wkva_bf, 737280);
  cvt_bf16_k<<<16384, 256, 0, stream>>>(wkvb, wkvb_bf, 4194304);

  // 2. q_a = hidden @ w_q_a^T  (f32 out)
  gemm_bt<0><<<dim3(12, 8), 256, 0, stream>>>(hid_bf, wqa_bf, HIDD, QLORA, qa_f, nullptr, nullptr);
  // 3. rmsnorm(q_a) -> bf16
  rmsnorm_k<<<1024, 256, 0, stream>>>(qa_f, QLORA, QLORA, gqa, qan_bf);
  // 4. q = qan @ w_q_b^T -> Q ws bf16 [b][h][qi][192]
  gemm_bt<1><<<dim3(192, 8), 256, 0, stream>>>(qan_bf, wqb_bf, QLORA, NHEAD * QHD, nullptr, nullptr, q_bf);
  // 5. ckv = hidden @ w_kv_a^T (padded 640 cols, f32)
  gemm_bt<0><<<dim3(5, 8), 256, 0, stream>>>(hid_bf, wkva_bf, HIDD, 640, ckv_f, nullptr, nullptr);
  // 6. rmsnorm(ckv[:, :512]) -> bf16
  rmsnorm_k<<<1024, 256, 0, stream>>>(ckv_f, 640, 512, gkva, ckvn_bf);
  // 7. kv = ckvn @ w_kv_b^T -> key f32+bf16 / value f32 (new rows)
  gemm_bt<2><<<dim3(256, 8), 256, 0, stream>>>(ckvn_bf, wkvb_bf, 512, NHEAD * 256, out_key, out_val, kb_bf);
  // 8. past concat copies + k_pe broadcast
  copy_key_past_k<<<24576, 256, 0, stream>>>(pk, out_key, kb_bf);
  copy_val_past_k<<<16384, 256, 0, stream>>>(pv, out_val);
  kpe_bcast_k<<<1024, 256, 0, stream>>>(ckv_f, out_key, kb_bf);
  // 9. V transpose -> Vt bf16
  transpose_v_k<<<4096, 256, 0, stream>>>(out_val, vt_bf);
  // 10. attention
  attn_k<<<1024, 256, 0, stream>>>(q_bf, kb_bf, vt_bf, mask, out_attn);
}

// Round 2
// 720.318 us; speedup vs baseline: 1.5417x; 1.5417x over previous
//
#include <hip/hip_runtime.h>

// ---------------- problem constants ----------------
#define NB    2
#define QLEN  512
#define HIDD  5120
#define QLORA 1536
#define NHEAD 128
#define QHD   192
#define VHD   128
#define KVTOT 1024
#define MROWS 1024  // NB*QLEN

typedef float          f32x4   __attribute__((ext_vector_type(4)));
typedef __bf16         bf16x8  __attribute__((ext_vector_type(8)));
typedef unsigned short u16x8   __attribute__((ext_vector_type(8)));
typedef unsigned short u16x4   __attribute__((ext_vector_type(4)));

static __device__ __forceinline__ unsigned short f2bf(float f) {
  union { float f; unsigned u; } v; v.f = f;
  return (unsigned short)((v.u + 0x7fffu + ((v.u >> 16) & 1u)) >> 16);
}

static __device__ __forceinline__ void g2l16(const void* g, void* l) {
  __builtin_amdgcn_global_load_lds(
      (const __attribute__((address_space(1))) void*)g,
      (__attribute__((address_space(3))) void*)l, 16, 0, 0);
}

// ---------------- f32 -> bf16 convert ----------------
__global__ __launch_bounds__(256) void cvt_bf16_k(const float* __restrict__ in,
                                                  unsigned short* __restrict__ out,
                                                  long n4) {
  long i = (long)blockIdx.x * 256 + threadIdx.x;
  if (i >= n4) return;
  f32x4 v = *(const f32x4*)(in + i * 4);
  u16x4 o;
  o[0] = f2bf(v[0]); o[1] = f2bf(v[1]); o[2] = f2bf(v[2]); o[3] = f2bf(v[3]);
  *(u16x4*)(out + i * 4) = o;
}

// ---------------- rmsnorm (one block per row) ----------------
__global__ __launch_bounds__(256) void rmsnorm_k(const float* __restrict__ in,
                                                 int instride, int cols,
                                                 const float* __restrict__ g,
                                                 unsigned short* __restrict__ out) {
  int row = blockIdx.x;
  int t = threadIdx.x, w = t >> 6, l = t & 63;
  const float* x = in + (long)row * instride;
  float xv[6];
  int nc = cols >> 8;
  float ss = 0.f;
  for (int i = 0; i < nc; ++i) { xv[i] = x[t + i * 256]; ss += xv[i] * xv[i]; }
  #pragma unroll
  for (int m = 32; m >= 1; m >>= 1) ss += __shfl_xor(ss, m);
  __shared__ float red[4];
  if (l == 0) red[w] = ss;
  __syncthreads();
  float tot = red[0] + red[1] + red[2] + red[3];
  float rs = rsqrtf(tot / (float)cols + 1e-6f);
  for (int i = 0; i < nc; ++i) {
    int c = t + i * 256;
    out[(long)row * cols + c] = f2bf(g[c] * xv[i] * rs);
  }
}

// ---------------- fused q_a + ckv GEMM: 128x64 tile, BK=64, 4 waves ----------------
// B = [w_q_a (1536 rows) ; w_kv_a (640 rows, last 64 zero-pad)], rows K-contig.
// cols < 1536 -> qa[row*1536+col]; else -> ckv[row*640+(col-1536)]
__global__ __launch_bounds__(256) void gemm_qa_ckv(const unsigned short* __restrict__ A,
                                                   const unsigned short* __restrict__ Bm,
                                                   float* __restrict__ qa,
                                                   float* __restrict__ ckv) {
  __shared__ __align__(16) unsigned short sA[128 * 64];
  __shared__ __align__(16) unsigned short sB[64 * 64];
  const int t = threadIdx.x, w = t >> 6, l = t & 63;
  const int l15 = l & 15, lh = l >> 4;
  const int mb = blockIdx.y, nb = blockIdx.x;
  const unsigned short* Ab = A + (long)mb * 128 * HIDD;
  const unsigned short* Bb = Bm + (long)nb * 64 * HIDD;
  f32x4 acc[2][4];
  #pragma unroll
  for (int i = 0; i < 2; ++i)
    #pragma unroll
    for (int j = 0; j < 4; ++j)
      #pragma unroll
      for (int r = 0; r < 4; ++r) acc[i][j][r] = 0.f;

  for (int kt = 0; kt < HIDD; kt += 64) {
    #pragma unroll
    for (int i2 = 0; i2 < 4; ++i2) {
      int n = i2 * 256 + t, r = n >> 3, c = n & 7;
      g2l16(Ab + (long)r * HIDD + kt + c * 8, (char*)sA + (i2 * 256 + w * 64) * 16);
    }
    #pragma unroll
    for (int i2 = 0; i2 < 2; ++i2) {
      int n = i2 * 256 + t, r = n >> 3, c = n & 7;
      g2l16(Bb + (long)r * HIDD + kt + c * 8, (char*)sB + (i2 * 256 + w * 64) * 16);
    }
    __syncthreads();
    #pragma unroll
    for (int ks = 0; ks < 2; ++ks) {
      bf16x8 af[2], bfr[4];
      #pragma unroll
      for (int i = 0; i < 2; ++i)
        af[i] = *(const bf16x8*)(sA + (w * 32 + i * 16 + l15) * 64 + ks * 32 + lh * 8);
      #pragma unroll
      for (int j = 0; j < 4; ++j)
        bfr[j] = *(const bf16x8*)(sB + (j * 16 + l15) * 64 + ks * 32 + lh * 8);
      #pragma unroll
      for (int i = 0; i < 2; ++i)
        #pragma unroll
        for (int j = 0; j < 4; ++j)
          acc[i][j] = __builtin_amdgcn_mfma_f32_16x16x32_bf16(af[i], bfr[j], acc[i][j], 0, 0, 0);
    }
    __syncthreads();
  }
  const int colbase = nb * 64;
  #pragma unroll
  for (int i = 0; i < 2; ++i) {
    #pragma unroll
    for (int j = 0; j < 4; ++j) {
      const int col = colbase + j * 16 + l15;
      #pragma unroll
      for (int r4 = 0; r4 < 4; ++r4) {
        const long row = (long)mb * 128 + w * 32 + i * 16 + lh * 4 + r4;
        const float v = acc[i][j][r4];
        if (colbase < 1536) qa[row * 1536 + col];
        if (colbase < 1536) qa[row * 1536 + col] = v;
        else                ckv[row * 640 + (col - 1536)] = v;
      }
    }
  }
}

// ---------------- bf16 B^T GEMM, 128x128 tile, BK=64, 4 waves ----------------
template <int EPI>
__global__ __launch_bounds__(256) void gemm_bt(const unsigned short* __restrict__ A,
                                               const unsigned short* __restrict__ Bm,
                                               int K, int N,
                                               float* __restrict__ o0,
                                               float* __restrict__ o1,
                                               unsigned short* __restrict__ u0) {
  __shared__ __align__(16) unsigned short sA[128 * 64];
  __shared__ __align__(16) unsigned short sB[128 * 64];
  const int t = threadIdx.x;
  const int w = t >> 6, l = t & 63;
  const int l15 = l & 15, lh = l >> 4;
  const int wm = w >> 1, wn = w & 1;
  const int mb = blockIdx.y, nb = blockIdx.x;
  const unsigned short* Ab = A + (long)mb * 128 * K;
  const unsigned short* Bb = Bm + (long)nb * 128 * K;
  f32x4 acc[4][4];
  #pragma unroll
  for (int i = 0; i < 4; ++i)
    #pragma unroll
    for (int j = 0; j < 4; ++j)
      #pragma unroll
      for (int r = 0; r < 4; ++r) acc[i][j][r] = 0.f;

  const int srow = l >> 3;
  const int scol = (l & 7) * 8;

  for (int kt = 0; kt < K; kt += 64) {
    #pragma unroll
    for (int i = 0; i < 4; ++i) {
      const int chunk = i * 4 + w;
      const int r = chunk * 8 + srow;
      g2l16(Ab + (long)r * K + kt + scol, (char*)sA + chunk * 1024);
      g2l16(Bb + (long)r * K + kt + scol, (char*)sB + chunk * 1024);
    }
    __syncthreads();
    #pragma unroll
    for (int ks = 0; ks < 2; ++ks) {
      bf16x8 af[4], bfr[4];
      #pragma unroll
      for (int i = 0; i < 4; ++i)
        af[i] = *(const bf16x8*)(sA + (wm * 64 + i * 16 + l15) * 64 + ks * 32 + lh * 8);
      #pragma unroll
      for (int j = 0; j < 4; ++j)
        bfr[j] = *(const bf16x8*)(sB + (wn * 64 + j * 16 + l15) * 64 + ks * 32 + lh * 8);
      #pragma unroll
      for (int i = 0; i < 4; ++i)
        #pragma unroll
        for (int j = 0; j < 4; ++j)
          acc[i][j] = __builtin_amdgcn_mfma_f32_16x16x32_bf16(af[i], bfr[j], acc[i][j], 0, 0, 0);
    }
    __syncthreads();
  }

  const long rowbase = (long)mb * 128 + wm * 64;
  const int colbase = nb * 128 + wn * 64;
  #pragma unroll
  for (int i = 0; i < 4; ++i) {
    #pragma unroll
    for (int j = 0; j < 4; ++j) {
      const int col = colbase + j * 16 + l15;
      #pragma unroll
      for (int r4 = 0; r4 < 4; ++r4) {
        const long row = rowbase + i * 16 + lh * 4 + r4;
        const float v = acc[i][j][r4];
        if (EPI == 1) {
          const int h = col / QHD, d = col - h * QHD;
          const long b_ = row >> 9, qi = row & 511;
          u0[(((b_ * NHEAD + h) * QLEN + qi)) * QHD + d] = f2bf(v);
        } else {
          const int h = col >> 8, d = col & 255;
          const long b_ = row >> 9, qi = row & 511;
          if (d < 128) {
            const long idx = ((b_ * NHEAD + h) * KVTOT + 512 + qi) * QHD + d;
            o0[idx] = v;
            u0[idx] = f2bf(v);
          } else {
            o1[((b_ * NHEAD + h) * KVTOT + 512 + qi) * VHD + (d - 128)] = v;
          }
        }
      }
    }
  }
}

// ---------------- past key copy: f32 out + bf16 ws ----------------
__global__ __launch_bounds__(256) void copy_key_past_k(const float* __restrict__ pk,
                                                       float* __restrict__ kout,
                                                       unsigned short* __restrict__ kb) {
  long i4 = (long)blockIdx.x * 256 + threadIdx.x;
  f32x4 v = *(const f32x4*)(pk + i4 * 4);
  long e = i4 * 4;
  long bh = e / 98304;
  long rem = e - bh * 98304;
  long oidx = bh * 196608 + rem;
  *(f32x4*)(kout + oidx) = v;
  u16x4 b;
  b[0] = f2bf(v[0]); b[1] = f2bf(v[1]); b[2] = f2bf(v[2]); b[3] = f2bf(v[3]);
  *(u16x4*)(kb + oidx) = b;
}

// ---------------- past value copy: f32 out ----------------
__global__ __launch_bounds__(256) void copy_val_past_k(const float* __restrict__ pv,
                                                       float* __restrict__ vout) {
  long i4 = (long)blockIdx.x * 256 + threadIdx.x;
  f32x4 v = *(const f32x4*)(pv + i4 * 4);
  long e = i4 * 4;
  long bh = e / 65536;
  long rem = e - bh * 65536;
  *(f32x4*)(vout + bh * 131072 + rem) = v;
}

// ---------------- k_pe broadcast into key output (all heads) ----------------
__global__ __launch_bounds__(256) void kpe_bcast_k(const float* __restrict__ ckv,
                                                   float* __restrict__ kout,
                                                   unsigned short* __restrict__ kb) {
  int bq = blockIdx.x;
  long b_ = bq >> 9, qi = bq & 511;
  int t = threadIdx.x;
  int j = t & 63, h0 = t >> 6;
  float v = ckv[(long)bq * 640 + 512 + j];
  unsigned short vb = f2bf(v);
  for (int h = h0; h < NHEAD; h += 4) {
    long idx = ((b_ * NHEAD + h) * KVTOT + 512 + qi) * QHD + 128 + j;
    kout[idx] = v;
    kb[idx] = vb;
  }
}

// ---------------- V transpose: Vout f32 [bh][1024][128] -> Vt bf16 [bh][128][1024] ----------------
__global__ __launch_bounds__(256) void transpose_v_k(const float* __restrict__ vout,
                                                     unsigned short* __restrict__ vt) {
  __shared__ __align__(16) unsigned short sT[128 * 72];
  int bh = blockIdx.x >> 4, kt = blockIdx.x & 15;
  int t = threadIdx.x;
  #pragma unroll
  for (int i = 0; i < 8; ++i) {
    int id = t + i * 256;
    int r = id >> 5, c4 = (id & 31) * 4;
    f32x4 v = *(const f32x4*)(vout + ((long)bh * KVTOT + kt * 64 + r) * VHD + c4);
    #pragma unroll
    for (int jj = 0; jj < 4; ++jj) sT[(c4 + jj) * 72 + r] = f2bf(v[jj]);
  }
  __syncthreads();
  #pragma unroll
  for (int i = 0; i < 4; ++i) {
    int id = t + i * 256;
    int d = id >> 3, c = id & 7;
    u16x8 v = *(const u16x8*)(sT + d * 72 + c * 8);
    *(u16x8*)(vt + ((long)bh * VHD + d) * KVTOT + kt * 64 + c * 8) = v;
  }
}

// ---------------- attention staging helpers (XOR-swizzled source, linear LDS dest) ----
static __device__ __forceinline__ void stage_k_tile(const unsigned short* __restrict__ src,
                                                    char* dstbase, int t) {
  const int w = t >> 6;
  #pragma unroll
  for (int i2 = 0; i2 < 6; ++i2) {
    int n = i2 * 256 + t;
    int r = n / 24, cp = n - r * 24;
    int c = cp ^ (r & 7);
    g2l16(src + (long)r * QHD + c * 8, dstbase + (i2 * 256 + w * 64) * 16);
  }
}

static __device__ __forceinline__ void stage_v_tile(const unsigned short* __restrict__ src,
                                                    char* dstbase, int t) {
  const int w = t >> 6;
  #pragma unroll
  for (int i2 = 0; i2 < 4; ++i2) {
    int n = i2 * 256 + t;
    int r = n >> 3, cp = n & 7;
    int c = cp ^ (r & 7);
    g2l16(src + (long)r * KVTOT + c * 8, dstbase + (i2 * 256 + w * 64) * 16);
  }
}

// ---------------- flash attention: 1 block = (b,h, 128-row q tile), 4 waves ----------------
// LDS 64 KB total -> 2 blocks/CU. sP aliased into sK[cur] (dead between QK^T and kt+2 stage).
__global__ __launch_bounds__(256, 2) void attn_k(const unsigned short* __restrict__ Qw,
                                                 const unsigned short* __restrict__ Kb,
                                                 const unsigned short* __restrict__ Vt,
                                                 const float* __restrict__ mask,
                                                 float* __restrict__ outp) {
  __shared__ __align__(16) unsigned short sK[2][64 * 192];
  __shared__ __align__(16) unsigned short sV[128 * 64];
  const int t = threadIdx.x, w = t >> 6, l = t & 63;
  const int l15 = l & 15, lh = l >> 4;
  // XCD-grouping remap: the 4 q-tiles of one bh land on the same XCD, consecutive slots.
  const int raw = blockIdx.x;
  const int xcd = raw & 7, slot = raw >> 3;
  const int bh = xcd * 32 + (slot >> 2), qt = slot & 3;
  const long b_ = bh >> 7;
  const float SCALE = 0.051023330039633184f;
  const int swz = l15 & 7;

  bf16x8 qf[2][6];
  const unsigned short* Qb = Qw + ((long)bh * QLEN + qt * 128 + w * 32) * QHD;
  #pragma unroll
  for (int i = 0; i < 2; ++i)
    #pragma unroll
    for (int ks = 0; ks < 6; ++ks)
      qf[i][ks] = *(const bf16x8*)(Qb + (i * 16 + l15) * QHD + ks * 32 + lh * 8);

  f32x4 o[2][8];
  #pragma unroll
  for (int i = 0; i < 2; ++i)
    #pragma unroll
    for (int j = 0; j < 8; ++j)
      #pragma unroll
      for (int r = 0; r < 4; ++r) o[i][j][r] = 0.f;
  float m_[2][4], l_[2][4];
  #pragma unroll
  for (int i = 0; i < 2; ++i)
    #pragma unroll
    for (int r = 0; r < 4; ++r) { m_[i][r] = -1e30f; l_[i][r] = 0.f; }

  const int qrow0 = qt * 128 + w * 32;
  const unsigned short* Kbh = Kb + (long)bh * KVTOT * QHD;
  const unsigned short* Vbh = Vt + (long)bh * VHD * KVTOT;
  const float* mrow = mask + b_ * 524288 + (long)(qrow0 + lh * 4) * 1024 + l15;

  // prologue: stage K tile 0
  stage_k_tile(Kbh, (char*)sK[0], t);
  __syncthreads();

  for (int kt = 0; kt < 16; ++kt) {
    const int cur = kt & 1;
    // issue next K tile + this V tile (async; drained by barrier #1)
    if (kt < 15) stage_k_tile(Kbh + (long)(kt + 1) * 64 * QHD, (char*)sK[cur ^ 1], t);
    stage_v_tile(Vbh + kt * 64, (char*)sV, t);

    // mask prefetch (off the softmax critical chain)
    float mreg[2][4][4];
    #pragma unroll
    for (int i = 0; i < 2; ++i)
      #pragma unroll
      for (int rg = 0; rg < 4; ++rg)
        #pragma unroll
        for (int j = 0; j < 4; ++j)
          mreg[i][rg][j] = mrow[(long)(i * 16 + rg) * 1024 + kt * 64 + j * 16];

    // S = Q K^T  (reads swizzled sK[cur])
    const unsigned short* sKc = sK[cur];
    f32x4 s[2][4];
    #pragma unroll
    for (int i = 0; i < 2; ++i)
      #pragma unroll
      for (int j = 0; j < 4; ++j)
        #pragma unroll
        for (int r = 0; r < 4; ++r) s[i][j][r] = 0.f;
    #pragma unroll
    for (int j = 0; j < 4; ++j) {
      #pragma unroll
      for (int ks = 0; ks < 6; ++ks) {
        bf16x8 kf = *(const bf16x8*)(sKc + ((j * 16 + l15) * 24 + ((ks * 4 + lh) ^ swz)) * 8);
        s[0][j] = __builtin_amdgcn_mfma_f32_16x16x32_bf16(qf[0][ks], kf, s[0][j], 0, 0, 0);
        s[1][j] = __builtin_amdgcn_mfma_f32_16x16x32_bf16(qf[1][ks], kf, s[1][j], 0, 0, 0);
      }
    }

    // online softmax -> p kept in registers
    unsigned short pk16[2][4][4];
    #pragma unroll
    for (int i = 0; i < 2; ++i) {
      #pragma unroll
      for (int rg = 0; rg < 4; ++rg) {
        float sc[4];
        #pragma unroll
        for (int j = 0; j < 4; ++j)
          sc[j] = s[i][j][rg] * SCALE + mreg[i][rg][j];
        float mx = fmaxf(fmaxf(sc[0], sc[1]), fmaxf(sc[2], sc[3]));
        mx = fmaxf(mx, __shfl_xor(mx, 1));
        mx = fmaxf(mx, __shfl_xor(mx, 2));
        mx = fmaxf(mx, __shfl_xor(mx, 4));
        mx = fmaxf(mx, __shfl_xor(mx, 8));
        float mo = m_[i][rg];
        float mn = fmaxf(mo, mx);
        float al = __expf(mo - mn);
        float rs = 0.f;
        #pragma unroll
        for (int j = 0; j < 4; ++j) {
          float p = __expf(sc[j] - mn);
          rs += p;
          pk16[i][rg][j] = f2bf(p);
        }
        rs += __shfl_xor(rs, 1);
        rs += __shfl_xor(rs, 2);
        rs += __shfl_xor(rs, 4);
        rs += __shfl_xor(rs, 8);
        l_[i][rg] = l_[i][rg] * al + rs;
        m_[i][rg] = mn;
        #pragma unroll
        for (int jj = 0; jj < 8; ++jj) o[i][jj][rg] *= al;
      }
    }
    __syncthreads();  // #1: all QK^T reads of sK[cur] done; staged loads drained

    // write P into sP (aliased into sK[cur] space), padded stride 72
    unsigned short* sPc = (unsigned short*)sK[cur];
    #pragma unroll
    for (int i = 0; i < 2; ++i)
      #pragma unroll
      for (int rg = 0; rg < 4; ++rg) {
        const int prow = w * 32 + i * 16 + lh * 4 + rg;
        #pragma unroll
        for (int j = 0; j < 4; ++j)
          sPc[prow * 72 + j * 16 + l15] = pk16[i][rg][j];
      }
    __syncthreads();  // #2: sP visible

    // O += P V  (reads swizzled sV)
    #pragma unroll
    for (int ks = 0; ks < 2; ++ks) {
      bf16x8 pf0 = *(const bf16x8*)(sPc + (w * 32 + l15) * 72 + ks * 32 + lh * 8);
      bf16x8 pf1 = *(const bf16x8*)(sPc + (w * 32 + 16 + l15) * 72 + ks * 32 + lh * 8);
      #pragma unroll
      for (int jj = 0; jj < 8; ++jj) {
        bf16x8 vf = *(const bf16x8*)(sV + ((jj * 16 + l15) * 8 + ((ks * 4 + lh) ^ swz)) * 8);
        o[0][jj] = __builtin_amdgcn_mfma_f32_16x16x32_bf16(pf0, vf, o[0][jj], 0, 0, 0);
        o[1][jj] = __builtin_amdgcn_mfma_f32_16x16x32_bf16(pf1, vf, o[1][jj], 0, 0, 0);
      }
    }
    __syncthreads();  // #3: PV done before next-iter stages overwrite sK[cur]/sV
  }

  #pragma unroll
  for (int i = 0; i < 2; ++i) {
    #pragma unroll
    for (int rg = 0; rg < 4; ++rg) {
      float inv = 1.0f / l_[i][rg];
      long row = (long)bh * QLEN + qrow0 + i * 16 + lh * 4 + rg;
      #pragma unroll
      for (int jj = 0; jj < 8; ++jj)
        outp[row * VHD + jj * 16 + l15] = o[i][jj][rg] * inv;
    }
  }
}

// ---------------- workspace layout (bytes) ----------------
#define WS_HID_BF   0L
#define WS_WQA_BF   10485760L    // 1536x5120 bf16 = 15,728,640
#define WS_WKVA_BF  26214400L    // 640x5120  bf16 =  6,553,600 (64 pad rows)
#define WS_WQB_BF   32768000L    // 24576x1536 bf16 = 75,497,472
#define WS_WKVB_BF  108265472L   // 32768x512 bf16 = 33,554,432
#define WS_QA_F32   141819904L
#define WS_QAN_BF   148111360L
#define WS_CKV_F32  151257088L
#define WS_CKVN_BF  153878528L
#define WS_Q_BF     154927104L
#define WS_KB_BF    205258752L
#define WS_VT_BF    305922048L
// total 373,030,912 bytes

extern "C" void kernel_launch(void* const* d_in, const int* in_sizes, int n_in,
                              void* d_out, int out_size, void* d_ws, size_t ws_size,
                              hipStream_t stream) {
  const float* hs   = (const float*)d_in[0];
  const float* mask = (const float*)d_in[1];
  const float* pk   = (const float*)d_in[2];
  const float* pv   = (const float*)d_in[3];
  const float* wqa  = (const float*)d_in[4];
  const float* gqa  = (const float*)d_in[5];
  const float* wqb  = (const float*)d_in[6];
  const float* wkva = (const float*)d_in[7];
  const float* gkva = (const float*)d_in[8];
  const float* wkvb = (const float*)d_in[9];

  char* ws = (char*)d_ws;
  unsigned short* hid_bf  = (unsigned short*)(ws + WS_HID_BF);
  unsigned short* wqa_bf  = (unsigned short*)(ws + WS_WQA_BF);   // stacked [wqa; wkva]
  unsigned short* wkva_bf = (unsigned short*)(ws + WS_WKVA_BF);
  unsigned short* wqb_bf  = (unsigned short*)(ws + WS_WQB_BF);
  unsigned short* wkvb_bf = (unsigned short*)(ws + WS_WKVB_BF);
  float*          qa_f    = (float*)(ws + WS_QA_F32);
  unsigned short* qan_bf  = (unsigned short*)(ws + WS_QAN_BF);
  float*          ckv_f   = (float*)(ws + WS_CKV_F32);
  unsigned short* ckvn_bf = (unsigned short*)(ws + WS_CKVN_BF);
  unsigned short* q_bf    = (unsigned short*)(ws + WS_Q_BF);
  unsigned short* kb_bf   = (unsigned short*)(ws + WS_KB_BF);
  unsigned short* vt_bf   = (unsigned short*)(ws + WS_VT_BF);

  float* out_attn = (float*)d_out;
  float* out_key  = (float*)d_out + 16777216;
  float* out_val  = (float*)d_out + 67108864;

  // 1. converts
  cvt_bf16_k<<<5120, 256, 0, stream>>>(hs,   hid_bf,  1310720);
  cvt_bf16_k<<<7680, 256, 0, stream>>>(wqa,  wqa_bf,  1966080);
  hipMemsetAsync(ws + WS_WKVA_BF + (long)576 * 5120 * 2, 0, (long)64 * 5120 * 2, stream);
  cvt_bf16_k<<<2880, 256, 0, stream>>>(wkva, wkva_bf, 737280);
  cvt_bf16_k<<<36864, 256, 0, stream>>>(wqb, wqb_bf,  9437184);
  cvt_bf16_k<<<16384, 256, 0, stream>>>(wkvb, wkvb_bf, 4194304);

  // 2. fused q_a + ckv GEMM (f32 out)
  gemm_qa_ckv<<<dim3(34, 8), 256, 0, stream>>>(hid_bf, wqa_bf, qa_f, ckv_f);
  // 3. rmsnorms -> bf16
  rmsnorm_k<<<1024, 256, 0, stream>>>(qa_f, QLORA, QLORA, gqa, qan_bf);
  rmsnorm_k<<<1024, 256, 0, stream>>>(ckv_f, 640, 512, gkva, ckvn_bf);
  // 4. q = qan @ w_q_b^T -> Q ws bf16 [b][h][qi][192]
  gemm_bt<1><<<dim3(192, 8), 256, 0, stream>>>(qan_bf, wqb_bf, QLORA, NHEAD * QHD, nullptr, nullptr, q_bf);
  // 5. kv = ckvn @ w_kv_b^T -> key f32+bf16 / value f32 (new rows)
  gemm_bt<2><<<dim3(256, 8), 256, 0, stream>>>(ckvn_bf, wkvb_bf, 512, NHEAD * 256, out_key, out_val, kb_bf);
  // 6. past concat copies + k_pe broadcast
  copy_key_past_k<<<24576, 256, 0, stream>>>(pk, out_key, kb_bf);
  copy_val_past_k<<<16384, 256, 0, stream>>>(pv, out_val);
  kpe_bcast_k<<<1024, 256, 0, stream>>>(ckv_f, out_key, kb_bf);
  // 7. V transpose -> Vt bf16
  transpose_v_k<<<4096, 256, 0, stream>>>(out_val, vt_bf);
  // 8. attention
  attn_k<<<1024, 256, 0, stream>>>(q_bf, kb_bf, vt_bf, mask, out_attn);
}